// Round 7
// baseline (1597.937 us; speedup 1.0000x reference)
//
#include <hip/hip_runtime.h>

#define NUu 100000
#define NIi 100000
#define NAa 10000
#define DD  64
#define NN0 (NUu + NIi)   // 200000
#define NN1 (NUu + NAa)   // 110000

typedef unsigned int uint;

// ---------------- bf16 helpers ----------------

__device__ __forceinline__ uint pack_bf2(float x, float y) {
    uint a = __float_as_uint(x);
    uint b = __float_as_uint(y);
    a = (a + 0x7fffu + ((a >> 16) & 1u)) >> 16;          // RNE low half
    b = (b + 0x7fffu + ((b >> 16) & 1u)) & 0xffff0000u;  // RNE high half
    return (a & 0xffffu) | b;
}
__device__ __forceinline__ float bflo(uint w) { return __uint_as_float(w << 16); }
__device__ __forceinline__ float bfhi(uint w) { return __uint_as_float(w & 0xffff0000u); }

// convert fp32 -> packed bf16x2 (float4 -> uint2), n4 = nfloats/4
__global__ void k_f2bf(const float4* __restrict__ src, uint2* __restrict__ dst, int n4) {
    int i = blockIdx.x * blockDim.x + threadIdx.x;
    if (i >= n4) return;
    float4 v = src[i];
    uint2 o;
    o.x = pack_bf2(v.x, v.y);
    o.y = pack_bf2(v.z, v.w);
    dst[i] = o;
}

// ---------------- CSR build (bin-partition, no global row histogram) ----------------

#define P1_ITER 8

// per-block LDS histogram over bins -> one global add per (block,bin)
__global__ void __launch_bounds__(1024)
k_binhist(const int* __restrict__ row, int* __restrict__ binCnt,
          int E, int shift, int nbins) {
    __shared__ int h[512];
    for (int t = threadIdx.x; t < nbins; t += blockDim.x) h[t] = 0;
    __syncthreads();
    int e0 = blockIdx.x * (blockDim.x * P1_ITER) + threadIdx.x;
#pragma unroll
    for (int i = 0; i < P1_ITER; ++i) {
        int e = e0 + i * blockDim.x;
        if (e < E) atomicAdd(&h[row[e] >> shift], 1);
    }
    __syncthreads();
    for (int t = threadIdx.x; t < nbins; t += blockDim.x)
        if (h[t]) atomicAdd(binCnt + t, h[t]);
}

// single-block exclusive scan of bin counts -> binBase (nbins+1), binCur
__global__ void k_binscan(const int* __restrict__ binCnt, int* __restrict__ binBase,
                          int* __restrict__ binCur, int nbins, int E) {
    __shared__ int s[512];
    int tid = threadIdx.x;
    int v = (tid < nbins) ? binCnt[tid] : 0;
    s[tid] = v;
    __syncthreads();
    for (int off = 1; off < 512; off <<= 1) {
        int t = (tid >= off) ? s[tid - off] : 0;
        __syncthreads();
        s[tid] += t;
        __syncthreads();
    }
    if (tid < nbins) {
        int b = s[tid] - v;
        binBase[tid] = b;
        binCur[tid] = b;
    }
    if (tid == 0) binBase[nbins] = E;
}

// P1: partition edges into per-bin staged segments; stage = {rowlow<<18 | col, val}
__global__ void __launch_bounds__(1024)
k_part1(const int* __restrict__ row, const int* __restrict__ col,
        const float* __restrict__ val, int* __restrict__ binCur,
        int2* __restrict__ stageP, int E, int shift, int nbins) {
    __shared__ int h[512];
    for (int t = threadIdx.x; t < nbins; t += blockDim.x) h[t] = 0;
    __syncthreads();
    int e0 = blockIdx.x * (blockDim.x * P1_ITER) + threadIdx.x;
    int r[P1_ITER];
#pragma unroll
    for (int i = 0; i < P1_ITER; ++i) {
        int e = e0 + i * blockDim.x;
        r[i] = (e < E) ? row[e] : -1;
        if (r[i] >= 0) atomicAdd(&h[r[i] >> shift], 1);
    }
    __syncthreads();
    for (int t = threadIdx.x; t < nbins; t += blockDim.x) {
        int c = h[t];
        h[t] = c ? atomicAdd(binCur + t, c) : 0;
    }
    __syncthreads();
#pragma unroll
    for (int i = 0; i < P1_ITER; ++i) {
        int e = e0 + i * blockDim.x;
        if (e < E) {
            int rr = r[i];
            int pos = atomicAdd(&h[rr >> shift], 1);
            int2 p;
            p.x = ((rr & ((1 << shift) - 1)) << 18) | col[e];
            p.y = __float_as_int(val[e]);
            stageP[pos] = p;
        }
    }
}

// P2: one block per bin. Count per-row in LDS, scan -> write rp, then exact placement.
__global__ void __launch_bounds__(1024)
k_part2(const int* __restrict__ binBase, const int2* __restrict__ stageP,
        int2* __restrict__ spair, int* __restrict__ rp, int N, int shift) {
    __shared__ int h[512];
    __shared__ int s[512];
    int tid = threadIdx.x;
    int rbase = blockIdx.x << shift;
    int nr = min(1 << shift, N - rbase);
    int es = binBase[blockIdx.x];
    int ee = binBase[blockIdx.x + 1];
    if (tid < 512) h[tid] = 0;
    __syncthreads();
    for (int i = es + tid; i < ee; i += blockDim.x)
        atomicAdd(&h[stageP[i].x >> 18], 1);
    __syncthreads();
    int v = (tid < 512) ? h[tid] : 0;
    if (tid < 512) s[tid] = v;
    __syncthreads();
    for (int off = 1; off < 512; off <<= 1) {
        int t = (tid < 512 && tid >= off) ? s[tid - off] : 0;
        __syncthreads();
        if (tid < 512) s[tid] += t;
        __syncthreads();
    }
    if (tid < 512) h[tid] = es + s[tid] - v;   // row cursor
    if (tid < nr) rp[rbase + tid] = es + s[tid] - v;
    if (tid == 0 && rbase + nr == N) rp[N] = ee;
    __syncthreads();
    for (int i = es + tid; i < ee; i += blockDim.x) {
        int2 p = stageP[i];
        int pos = atomicAdd(&h[p.x >> 18], 1);
        int2 o;
        o.x = p.x & 0x3ffff;
        o.y = p.y;
        spair[pos] = o;
    }
}

// ---------------- SpMM (bf16 gather, one wave = one row, 2 edges/step, 8-deep) ----------------

__device__ __forceinline__ long long ntl(const int2* p) {
    return __builtin_nontemporal_load((const long long*)p);
}

template <bool SS>
__device__ __forceinline__ const uint* gb(long long q, const uint* xbA, const uint* xbB,
                                          int split) {
    int c = (int)q;
    if (SS) return (c < split) ? xbA + (((long long)c) << 5)
                               : xbB + (((long long)(c - split)) << 5);
    return xbA + (((long long)c) << 5);
}

// MODE 0: plain  — ob = pack(a)   (nontemporal)
// MODE 1: final  — out = 0.25*(emb + y1 + y2 + a); fp32 out split U/I, optional bf16 outIb
// MODE 2: norm   — yf = normalize(a)
// MODE 3: blend  — yf = 0.5*normalize(a) + 0.5*base
template <int MODE, bool SS>
__global__ void k_spmm(const int* __restrict__ rp, const int2* __restrict__ sp,
                       const uint* __restrict__ xbA, const uint* __restrict__ xbB, int split,
                       const float* __restrict__ embA, const float* __restrict__ embB,
                       const uint* __restrict__ y1b, const uint* __restrict__ y2b,
                       float* __restrict__ outU, float* __restrict__ outI,
                       uint* __restrict__ outIb,
                       uint* __restrict__ ob, float* __restrict__ yf,
                       const float* __restrict__ base, int nrows) {
    int r = blockIdx.x * (blockDim.x >> 6) + (threadIdx.x >> 6);
    if (r >= nrows) return;
    int lane = threadIdx.x & 63;
    int half = lane >> 5;
    int dp = lane & 31;

    int s0 = rp[r], e0 = rp[r + 1];
    float ax = 0.f, ay = 0.f;
    int i = s0;
    for (; i + 8 <= e0; i += 8) {
        long long q0 = ntl(sp + i + half);
        long long q1 = ntl(sp + i + 2 + half);
        long long q2 = ntl(sp + i + 4 + half);
        long long q3 = ntl(sp + i + 6 + half);
        uint w0 = gb<SS>(q0, xbA, xbB, split)[dp];
        uint w1 = gb<SS>(q1, xbA, xbB, split)[dp];
        uint w2 = gb<SS>(q2, xbA, xbB, split)[dp];
        uint w3 = gb<SS>(q3, xbA, xbB, split)[dp];
        float v0 = __int_as_float((int)(q0 >> 32));
        float v1 = __int_as_float((int)(q1 >> 32));
        float v2 = __int_as_float((int)(q2 >> 32));
        float v3 = __int_as_float((int)(q3 >> 32));
        ax += v0 * bflo(w0); ay += v0 * bfhi(w0);
        ax += v1 * bflo(w1); ay += v1 * bfhi(w1);
        ax += v2 * bflo(w2); ay += v2 * bfhi(w2);
        ax += v3 * bflo(w3); ay += v3 * bfhi(w3);
    }
    for (; i + 2 <= e0; i += 2) {
        long long q = ntl(sp + i + half);
        uint w = gb<SS>(q, xbA, xbB, split)[dp];
        float v = __int_as_float((int)(q >> 32));
        ax += v * bflo(w); ay += v * bfhi(w);
    }
    if (i < e0) {
        long long q = (half == 0) ? ntl(sp + i) : 0;   // col 0, val 0 pad
        uint w = gb<SS>(q, xbA, xbB, split)[dp];
        float v = __int_as_float((int)(q >> 32));
        ax += v * bflo(w); ay += v * bfhi(w);
    }
    ax += __shfl_xor(ax, 32);
    ay += __shfl_xor(ay, 32);

    long long off2 = (((long long)r) << 6) + 2 * dp;

    if (MODE == 0) {
        if (half == 0)
            __builtin_nontemporal_store(pack_bf2(ax, ay), ob + (((long long)r) << 5) + dp);
    } else if (MODE == 1) {
        if (half == 0) {
            float2 e2;
            if (r < split) e2 = *(const float2*)(embA + off2);
            else           e2 = *(const float2*)(embB + (off2 - (((long long)split) << 6)));
            uint w1 = y1b[(((long long)r) << 5) + dp];
            uint w2 = y2b[(((long long)r) << 5) + dp];
            float sx = 0.25f * (e2.x + bflo(w1) + bflo(w2) + ax);
            float sy = 0.25f * (e2.y + bfhi(w1) + bfhi(w2) + ay);
            if (r < split) {
                float2 o; o.x = sx; o.y = sy;
                *(float2*)(outU + off2) = o;
            } else {
                long long o2 = off2 - (((long long)split) << 6);
                float2 o; o.x = sx; o.y = sy;
                *(float2*)(outI + o2) = o;
                if (outIb)
                    __builtin_nontemporal_store(pack_bf2(sx, sy),
                                                outIb + (((long long)(r - split)) << 5) + dp);
            }
        }
    } else {
        float sq = ax * ax + ay * ay;
        for (int m = 16; m; m >>= 1) sq += __shfl_xor(sq, m);
        float inv = 1.0f / fmaxf(sqrtf(sq), 1e-12f);
        if (half == 0) {
            float2 o;
            if (MODE == 2) { o.x = ax * inv; o.y = ay * inv; }
            else {
                float2 b2 = *(const float2*)(base + off2);
                o.x = 0.5f * ax * inv + 0.5f * b2.x;
                o.y = 0.5f * ay * inv + 0.5f * b2.y;
            }
            *(float2*)(yf + off2) = o;
        }
    }
}

// ---------------- host ----------------

static inline int nblk(long long n, int b) { return (int)((n + b - 1) / b); }
static inline size_t al256(size_t x) { return (x + 255) & ~(size_t)255; }

extern "C" void kernel_launch(void* const* d_in, const int* in_sizes, int n_in,
                              void* d_out, int out_size, void* d_ws, size_t ws_size,
                              hipStream_t stream) {
    const float* emb_user   = (const float*)d_in[0];
    const float* emb_item   = (const float*)d_in[1];
    const float* emb_author = (const float*)d_in[2];
    const int*   g0r = (const int*)d_in[3];
    const int*   g0c = (const int*)d_in[4];
    const float* g0v = (const float*)d_in[5];
    const int*   g1r = (const int*)d_in[6];
    const int*   g1c = (const int*)d_in[7];
    const float* g1v = (const float*)d_in[8];
    const int*   g3r = (const int*)d_in[9];
    const int*   g3c = (const int*)d_in[10];
    const float* g3v = (const float*)d_in[11];
    const int*   g4r = (const int*)d_in[12];
    const int*   g4c = (const int*)d_in[13];
    const float* g4v = (const float*)d_in[14];
    const int*   g5r = (const int*)d_in[15];
    const int*   g5c = (const int*)d_in[16];
    const float* g5v = (const float*)d_in[17];

    const int E0 = in_sizes[3];
    const int E1 = in_sizes[6];
    const int E3 = in_sizes[9];
    const int E4 = in_sizes[12];
    const int E5 = in_sizes[15];

    float* out = (float*)d_out;

    // ---- workspace carve-up ----
    char* w = (char*)d_ws;
    int*  rp      = (int*)w;  w += al256((size_t)(NN0 + 1) * 4);
    int*  binCnt  = (int*)w;  w += al256((size_t)512 * 4);
    int*  binBase = (int*)w;  w += al256((size_t)513 * 4);
    int*  binCur  = (int*)w;  w += al256((size_t)512 * 4);
    int2* spair   = (int2*)w; w += al256((size_t)6400000 * 8);
    uint* embUb   = (uint*)w; w += al256((size_t)NUu * 32 * 4);   // bf16 embeddings
    uint* embIb   = (uint*)w; w += al256((size_t)NIi * 32 * 4);
    uint* embAb   = (uint*)w; w += al256((size_t)NAa * 32 * 4);
    uint* y1b     = (uint*)w; w += al256((size_t)NN0 * 32 * 4);   // bf16 layer outs
    uint* y2b     = (uint*)w; w += al256((size_t)NN0 * 32 * 4);
    float* items0  = (float*)w; w += al256((size_t)NIi * DD * 4); // fp32 atom_items0
    uint*  items0b = (uint*)w;  w += al256((size_t)NIi * 32 * 4); // bf16 atom_items0
    uint*  oAuthNb = (uint*)w;  w += al256((size_t)NAa * 32 * 4); // bf16 non_atom_authors
    // staging aliases y1b+y2b (dead during builds): E*8 <= 51.2MB
    int2* stageP = (int2*)y1b;

    const int B = 256;

    auto build_csr = [&](const int* row, const int* col, const float* val,
                         int E, int N, int shift) {
        int nbins = (N + (1 << shift) - 1) >> shift;
        hipMemsetAsync(binCnt, 0, (size_t)nbins * sizeof(int), stream);
        k_binhist<<<nblk(E, 1024 * P1_ITER), 1024, 0, stream>>>(row, binCnt, E, shift, nbins);
        k_binscan<<<1, 512, 0, stream>>>(binCnt, binBase, binCur, nbins, E);
        k_part1<<<nblk(E, 1024 * P1_ITER), 1024, 0, stream>>>(row, col, val, binCur,
                                                              stageP, E, shift, nbins);
        k_part2<<<nbins, 1024, 0, stream>>>(binBase, stageP, spair, rp, N, shift);
    };

    float* oUserA = out;                            // atom_users
    float* oUserN = out + (long long)NUu * DD;      // non_atom_users
    float* oItemA = out + (long long)200000 * DD;   // atom_items
    float* oItemN = out + (long long)300000 * DD;   // non_atom_items
    float* oAuthA = out + (long long)400000 * DD;   // atom_authors
    float* oAuthN = out + (long long)410000 * DD;   // non_atom_authors

    // ---- convert all embeddings to bf16 once ----
    k_f2bf<<<nblk((long long)NUu * 16, B), B, 0, stream>>>((const float4*)emb_user,
                                                           (uint2*)embUb, NUu * 16);
    k_f2bf<<<nblk((long long)NIi * 16, B), B, 0, stream>>>((const float4*)emb_item,
                                                           (uint2*)embIb, NIi * 16);
    k_f2bf<<<nblk((long long)NAa * 16, B), B, 0, stream>>>((const float4*)emb_author,
                                                           (uint2*)embAb, NAa * 16);

    // ========== atom branch: 3-layer propagate on g0 ==========
    build_csr(g0r, g0c, g0v, E0, NN0, 9);
    k_spmm<0, true><<<nblk(NN0, 4), B, 0, stream>>>(rp, spair, embUb, embIb, NUu,
                                                    nullptr, nullptr, nullptr, nullptr,
                                                    nullptr, nullptr, nullptr,
                                                    y1b, nullptr, nullptr, NN0);
    k_spmm<0, false><<<nblk(NN0, 4), B, 0, stream>>>(rp, spair, y1b, nullptr, 0,
                                                     nullptr, nullptr, nullptr, nullptr,
                                                     nullptr, nullptr, nullptr,
                                                     y2b, nullptr, nullptr, NN0);
    k_spmm<1, false><<<nblk(NN0, 4), B, 0, stream>>>(rp, spair, y2b, nullptr, NUu,
                                                     emb_user, emb_item, y1b, y2b,
                                                     oUserA, items0, items0b,
                                                     nullptr, nullptr, nullptr, NN0);

    // ========== non-atom branch: 3-layer propagate on g1 ==========
    build_csr(g1r, g1c, g1v, E1, NN1, 9);
    k_spmm<0, true><<<nblk(NN1, 4), B, 0, stream>>>(rp, spair, embUb, embAb, NUu,
                                                    nullptr, nullptr, nullptr, nullptr,
                                                    nullptr, nullptr, nullptr,
                                                    y1b, nullptr, nullptr, NN1);
    k_spmm<0, false><<<nblk(NN1, 4), B, 0, stream>>>(rp, spair, y1b, nullptr, 0,
                                                     nullptr, nullptr, nullptr, nullptr,
                                                     nullptr, nullptr, nullptr,
                                                     y2b, nullptr, nullptr, NN1);
    k_spmm<1, false><<<nblk(NN1, 4), B, 0, stream>>>(rp, spair, y2b, nullptr, NUu,
                                                     emb_user, emb_author, y1b, y2b,
                                                     oUserN, oAuthN, oAuthNb,
                                                     nullptr, nullptr, nullptr, NN1);

    // ========== atom_authors = normalize(g3 @ items0) ==========
    build_csr(g3r, g3c, g3v, E3, NAa, 5);
    k_spmm<2, false><<<nblk(NAa, 4), B, 0, stream>>>(rp, spair, items0b, nullptr, 0,
                                                     nullptr, nullptr, nullptr, nullptr,
                                                     nullptr, nullptr, nullptr,
                                                     nullptr, oAuthA, nullptr, NAa);

    // ========== atom_items = 0.5*normalize(g5 @ items0) + 0.5*items0 ==========
    build_csr(g5r, g5c, g5v, E5, NIi, 8);
    k_spmm<3, false><<<nblk(NIi, 4), B, 0, stream>>>(rp, spair, items0b, nullptr, 0,
                                                     nullptr, nullptr, nullptr, nullptr,
                                                     nullptr, nullptr, nullptr,
                                                     nullptr, oItemA, items0, NIi);

    // ========== non_atom_items = normalize(g4 @ non_atom_authors) ==========
    build_csr(g4r, g4c, g4v, E4, NIi, 8);
    k_spmm<2, false><<<nblk(NIi, 4), B, 0, stream>>>(rp, spair, oAuthNb, nullptr, 0,
                                                     nullptr, nullptr, nullptr, nullptr,
                                                     nullptr, nullptr, nullptr,
                                                     nullptr, oItemN, nullptr, NIi);
}

// Round 8
// 1369.514 us; speedup vs baseline: 1.1668x; 1.1668x over previous
//
#include <hip/hip_runtime.h>

#define NUu 100000
#define NIi 100000
#define NAa 10000
#define DD  64
#define NN0 (NUu + NIi)   // 200000
#define NN1 (NUu + NAa)   // 110000

typedef unsigned int uint;

// ---------------- bf16 helpers ----------------

__device__ __forceinline__ uint pack_bf2(float x, float y) {
    uint a = __float_as_uint(x);
    uint b = __float_as_uint(y);
    a = (a + 0x7fffu + ((a >> 16) & 1u)) >> 16;          // RNE low half
    b = (b + 0x7fffu + ((b >> 16) & 1u)) & 0xffff0000u;  // RNE high half
    return (a & 0xffffu) | b;
}
__device__ __forceinline__ float bflo(uint w) { return __uint_as_float(w << 16); }
__device__ __forceinline__ float bfhi(uint w) { return __uint_as_float(w & 0xffff0000u); }

// convert fp32 -> packed bf16x2 (float4 -> uint2), n4 = nfloats/4
__global__ void k_f2bf(const float4* __restrict__ src, uint2* __restrict__ dst, int n4) {
    int i = blockIdx.x * blockDim.x + threadIdx.x;
    if (i >= n4) return;
    float4 v = src[i];
    uint2 o;
    o.x = pack_bf2(v.x, v.y);
    o.y = pack_bf2(v.z, v.w);
    dst[i] = o;
}

// ---------------- CSR build (bin-partition, no global row histogram) ----------------

#define P1_ITER 8
#define SEG_CAP 18944     // LDS-staged edges per bin in k_part2 (148KB)

// per-block LDS histogram over bins -> one global add per (block,bin)
__global__ void __launch_bounds__(1024)
k_binhist(const int* __restrict__ row, int* __restrict__ binCnt,
          int E, int shift, int nbins) {
    __shared__ int h[512];
    for (int t = threadIdx.x; t < nbins; t += blockDim.x) h[t] = 0;
    __syncthreads();
    int e0 = blockIdx.x * (blockDim.x * P1_ITER) + threadIdx.x;
#pragma unroll
    for (int i = 0; i < P1_ITER; ++i) {
        int e = e0 + i * blockDim.x;
        if (e < E) atomicAdd(&h[row[e] >> shift], 1);
    }
    __syncthreads();
    for (int t = threadIdx.x; t < nbins; t += blockDim.x)
        if (h[t]) atomicAdd(binCnt + t, h[t]);
}

// single-block exclusive scan of bin counts -> binBase (nbins+1), binCur
__global__ void k_binscan(const int* __restrict__ binCnt, int* __restrict__ binBase,
                          int* __restrict__ binCur, int nbins, int E) {
    __shared__ int s[512];
    int tid = threadIdx.x;
    int v = (tid < nbins) ? binCnt[tid] : 0;
    s[tid] = v;
    __syncthreads();
    for (int off = 1; off < 512; off <<= 1) {
        int t = (tid >= off) ? s[tid - off] : 0;
        __syncthreads();
        s[tid] += t;
        __syncthreads();
    }
    if (tid < nbins) {
        int b = s[tid] - v;
        binBase[tid] = b;
        binCur[tid] = b;
    }
    if (tid == 0) binBase[nbins] = E;
}

// P1: partition edges into per-bin staged segments; stage = {rowlow<<18 | col, val}
__global__ void __launch_bounds__(1024)
k_part1(const int* __restrict__ row, const int* __restrict__ col,
        const float* __restrict__ val, int* __restrict__ binCur,
        int2* __restrict__ stageP, int E, int shift, int nbins) {
    __shared__ int h[512];
    for (int t = threadIdx.x; t < nbins; t += blockDim.x) h[t] = 0;
    __syncthreads();
    int e0 = blockIdx.x * (blockDim.x * P1_ITER) + threadIdx.x;
    int r[P1_ITER];
#pragma unroll
    for (int i = 0; i < P1_ITER; ++i) {
        int e = e0 + i * blockDim.x;
        r[i] = (e < E) ? row[e] : -1;
        if (r[i] >= 0) atomicAdd(&h[r[i] >> shift], 1);
    }
    __syncthreads();
    for (int t = threadIdx.x; t < nbins; t += blockDim.x) {
        int c = h[t];
        h[t] = c ? atomicAdd(binCur + t, c) : 0;
    }
    __syncthreads();
#pragma unroll
    for (int i = 0; i < P1_ITER; ++i) {
        int e = e0 + i * blockDim.x;
        if (e < E) {
            int rr = r[i];
            int pos = atomicAdd(&h[rr >> shift], 1);
            int2 p;
            p.x = ((rr & ((1 << shift) - 1)) << 18) | col[e];
            p.y = __float_as_int(val[e]);
            stageP[pos] = p;
        }
    }
}

// P2: one block per bin. Stage bin segment in LDS once, count per-row, scan -> rp,
// then exact placement — reads stageP from global exactly once.
__global__ void __launch_bounds__(1024)
k_part2(const int* __restrict__ binBase, const int2* __restrict__ stageP,
        int2* __restrict__ spair, int* __restrict__ rp, int N, int shift) {
    __shared__ int2 seg[SEG_CAP];
    __shared__ int h[512];
    __shared__ int s[512];
    int tid = threadIdx.x;
    int rbase = blockIdx.x << shift;
    int nr = min(1 << shift, N - rbase);
    int es = binBase[blockIdx.x];
    int ee = binBase[blockIdx.x + 1];
    int n = ee - es;
    bool inLds = (n <= SEG_CAP);
    if (tid < 512) h[tid] = 0;
    if (inLds)
        for (int i = tid; i < n; i += blockDim.x) seg[i] = stageP[es + i];
    __syncthreads();
    if (inLds) {
        for (int i = tid; i < n; i += blockDim.x)
            atomicAdd(&h[seg[i].x >> 18], 1);
    } else {
        for (int i = es + tid; i < ee; i += blockDim.x)
            atomicAdd(&h[stageP[i].x >> 18], 1);
    }
    __syncthreads();
    int v = (tid < 512) ? h[tid] : 0;
    if (tid < 512) s[tid] = v;
    __syncthreads();
    for (int off = 1; off < 512; off <<= 1) {
        int t = (tid < 512 && tid >= off) ? s[tid - off] : 0;
        __syncthreads();
        if (tid < 512) s[tid] += t;
        __syncthreads();
    }
    if (tid < 512) h[tid] = es + s[tid] - v;   // row cursor
    if (tid < nr) rp[rbase + tid] = es + s[tid] - v;
    if (tid == 0 && rbase + nr == N) rp[N] = ee;
    __syncthreads();
    if (inLds) {
        for (int i = tid; i < n; i += blockDim.x) {
            int2 p = seg[i];
            int pos = atomicAdd(&h[p.x >> 18], 1);
            int2 o;
            o.x = p.x & 0x3ffff;
            o.y = p.y;
            spair[pos] = o;
        }
    } else {
        for (int i = es + tid; i < ee; i += blockDim.x) {
            int2 p = stageP[i];
            int pos = atomicAdd(&h[p.x >> 18], 1);
            int2 o;
            o.x = p.x & 0x3ffff;
            o.y = p.y;
            spair[pos] = o;
        }
    }
}

// ---------------- SpMM (bf16 gather, one wave = one row, 2 edges/step, 8-deep) ----------------

template <bool SS>
__device__ __forceinline__ const uint* gb(long long q, const uint* xbA, const uint* xbB,
                                          int split) {
    int c = (int)q;
    if (SS) return (c < split) ? xbA + (((long long)c) << 5)
                               : xbB + (((long long)(c - split)) << 5);
    return xbA + (((long long)c) << 5);
}

// MODE 0: plain  — ob = pack(a)
// MODE 1: final  — out = 0.25*(emb + y1 + y2 + a); fp32 out split U/I, optional bf16 outIb
// MODE 2: norm   — yf = normalize(a)
// MODE 3: blend  — yf = 0.5*normalize(a) + 0.5*base
template <int MODE, bool SS>
__global__ void k_spmm(const int* __restrict__ rp, const int2* __restrict__ sp,
                       const uint* __restrict__ xbA, const uint* __restrict__ xbB, int split,
                       const float* __restrict__ embA, const float* __restrict__ embB,
                       const uint* __restrict__ y1b, const uint* __restrict__ y2b,
                       float* __restrict__ outU, float* __restrict__ outI,
                       uint* __restrict__ outIb,
                       uint* __restrict__ ob, float* __restrict__ yf,
                       const float* __restrict__ base, int nrows) {
    int r = blockIdx.x * (blockDim.x >> 6) + (threadIdx.x >> 6);
    if (r >= nrows) return;
    int lane = threadIdx.x & 63;
    int half = lane >> 5;
    int dp = lane & 31;

    int s0 = rp[r], e0 = rp[r + 1];
    float ax = 0.f, ay = 0.f;
    int i = s0;
    for (; i + 8 <= e0; i += 8) {
        long long q0 = *(const long long*)(sp + i + half);
        long long q1 = *(const long long*)(sp + i + 2 + half);
        long long q2 = *(const long long*)(sp + i + 4 + half);
        long long q3 = *(const long long*)(sp + i + 6 + half);
        uint w0 = gb<SS>(q0, xbA, xbB, split)[dp];
        uint w1 = gb<SS>(q1, xbA, xbB, split)[dp];
        uint w2 = gb<SS>(q2, xbA, xbB, split)[dp];
        uint w3 = gb<SS>(q3, xbA, xbB, split)[dp];
        float v0 = __int_as_float((int)(q0 >> 32));
        float v1 = __int_as_float((int)(q1 >> 32));
        float v2 = __int_as_float((int)(q2 >> 32));
        float v3 = __int_as_float((int)(q3 >> 32));
        ax += v0 * bflo(w0); ay += v0 * bfhi(w0);
        ax += v1 * bflo(w1); ay += v1 * bfhi(w1);
        ax += v2 * bflo(w2); ay += v2 * bfhi(w2);
        ax += v3 * bflo(w3); ay += v3 * bfhi(w3);
    }
    for (; i + 2 <= e0; i += 2) {
        long long q = *(const long long*)(sp + i + half);
        uint w = gb<SS>(q, xbA, xbB, split)[dp];
        float v = __int_as_float((int)(q >> 32));
        ax += v * bflo(w); ay += v * bfhi(w);
    }
    if (i < e0) {
        long long q = (half == 0) ? *(const long long*)(sp + i) : 0;   // col 0, val 0 pad
        uint w = gb<SS>(q, xbA, xbB, split)[dp];
        float v = __int_as_float((int)(q >> 32));
        ax += v * bflo(w); ay += v * bfhi(w);
    }
    ax += __shfl_xor(ax, 32);
    ay += __shfl_xor(ay, 32);

    long long off2 = (((long long)r) << 6) + 2 * dp;

    if (MODE == 0) {
        if (half == 0) ob[(((long long)r) << 5) + dp] = pack_bf2(ax, ay);
    } else if (MODE == 1) {
        if (half == 0) {
            float2 e2;
            if (r < split) e2 = *(const float2*)(embA + off2);
            else           e2 = *(const float2*)(embB + (off2 - (((long long)split) << 6)));
            uint w1 = y1b[(((long long)r) << 5) + dp];
            uint w2 = y2b[(((long long)r) << 5) + dp];
            float sx = 0.25f * (e2.x + bflo(w1) + bflo(w2) + ax);
            float sy = 0.25f * (e2.y + bfhi(w1) + bfhi(w2) + ay);
            if (r < split) {
                float2 o; o.x = sx; o.y = sy;
                *(float2*)(outU + off2) = o;
            } else {
                long long o2 = off2 - (((long long)split) << 6);
                float2 o; o.x = sx; o.y = sy;
                *(float2*)(outI + o2) = o;
                if (outIb)
                    outIb[(((long long)(r - split)) << 5) + dp] = pack_bf2(sx, sy);
            }
        }
    } else {
        float sq = ax * ax + ay * ay;
        for (int m = 16; m; m >>= 1) sq += __shfl_xor(sq, m);
        float inv = 1.0f / fmaxf(sqrtf(sq), 1e-12f);
        if (half == 0) {
            float2 o;
            if (MODE == 2) { o.x = ax * inv; o.y = ay * inv; }
            else {
                float2 b2 = *(const float2*)(base + off2);
                o.x = 0.5f * ax * inv + 0.5f * b2.x;
                o.y = 0.5f * ay * inv + 0.5f * b2.y;
            }
            *(float2*)(yf + off2) = o;
        }
    }
}

// ---------------- host ----------------

static inline int nblk(long long n, int b) { return (int)((n + b - 1) / b); }
static inline size_t al256(size_t x) { return (x + 255) & ~(size_t)255; }

extern "C" void kernel_launch(void* const* d_in, const int* in_sizes, int n_in,
                              void* d_out, int out_size, void* d_ws, size_t ws_size,
                              hipStream_t stream) {
    const float* emb_user   = (const float*)d_in[0];
    const float* emb_item   = (const float*)d_in[1];
    const float* emb_author = (const float*)d_in[2];
    const int*   g0r = (const int*)d_in[3];
    const int*   g0c = (const int*)d_in[4];
    const float* g0v = (const float*)d_in[5];
    const int*   g1r = (const int*)d_in[6];
    const int*   g1c = (const int*)d_in[7];
    const float* g1v = (const float*)d_in[8];
    const int*   g3r = (const int*)d_in[9];
    const int*   g3c = (const int*)d_in[10];
    const float* g3v = (const float*)d_in[11];
    const int*   g4r = (const int*)d_in[12];
    const int*   g4c = (const int*)d_in[13];
    const float* g4v = (const float*)d_in[14];
    const int*   g5r = (const int*)d_in[15];
    const int*   g5c = (const int*)d_in[16];
    const float* g5v = (const float*)d_in[17];

    const int E0 = in_sizes[3];
    const int E1 = in_sizes[6];
    const int E3 = in_sizes[9];
    const int E4 = in_sizes[12];
    const int E5 = in_sizes[15];

    float* out = (float*)d_out;

    // ---- workspace carve-up ----
    char* w = (char*)d_ws;
    int*  rp      = (int*)w;  w += al256((size_t)(NN0 + 1) * 4);
    int*  binCnt  = (int*)w;  w += al256((size_t)512 * 4);
    int*  binBase = (int*)w;  w += al256((size_t)513 * 4);
    int*  binCur  = (int*)w;  w += al256((size_t)512 * 4);
    int2* spair   = (int2*)w; w += al256((size_t)6400000 * 8);
    uint* embUb   = (uint*)w; w += al256((size_t)NUu * 32 * 4);   // bf16 embeddings
    uint* embIb   = (uint*)w; w += al256((size_t)NIi * 32 * 4);
    uint* embAb   = (uint*)w; w += al256((size_t)NAa * 32 * 4);
    uint* y1b     = (uint*)w; w += al256((size_t)NN0 * 32 * 4);   // bf16 layer outs
    uint* y2b     = (uint*)w; w += al256((size_t)NN0 * 32 * 4);
    float* items0  = (float*)w; w += al256((size_t)NIi * DD * 4); // fp32 atom_items0
    uint*  items0b = (uint*)w;  w += al256((size_t)NIi * 32 * 4); // bf16 atom_items0
    uint*  oAuthNb = (uint*)w;  w += al256((size_t)NAa * 32 * 4); // bf16 non_atom_authors
    // staging aliases y1b+y2b (dead during builds): E*8 <= 51.2MB
    int2* stageP = (int2*)y1b;

    const int B = 256;

    auto build_csr = [&](const int* row, const int* col, const float* val,
                         int E, int N, int shift) {
        int nbins = (N + (1 << shift) - 1) >> shift;
        hipMemsetAsync(binCnt, 0, (size_t)nbins * sizeof(int), stream);
        k_binhist<<<nblk(E, 1024 * P1_ITER), 1024, 0, stream>>>(row, binCnt, E, shift, nbins);
        k_binscan<<<1, 512, 0, stream>>>(binCnt, binBase, binCur, nbins, E);
        k_part1<<<nblk(E, 1024 * P1_ITER), 1024, 0, stream>>>(row, col, val, binCur,
                                                              stageP, E, shift, nbins);
        k_part2<<<nbins, 1024, 0, stream>>>(binBase, stageP, spair, rp, N, shift);
    };

    float* oUserA = out;                            // atom_users
    float* oUserN = out + (long long)NUu * DD;      // non_atom_users
    float* oItemA = out + (long long)200000 * DD;   // atom_items
    float* oItemN = out + (long long)300000 * DD;   // non_atom_items
    float* oAuthA = out + (long long)400000 * DD;   // atom_authors
    float* oAuthN = out + (long long)410000 * DD;   // non_atom_authors

    // ---- convert all embeddings to bf16 once ----
    k_f2bf<<<nblk((long long)NUu * 16, B), B, 0, stream>>>((const float4*)emb_user,
                                                           (uint2*)embUb, NUu * 16);
    k_f2bf<<<nblk((long long)NIi * 16, B), B, 0, stream>>>((const float4*)emb_item,
                                                           (uint2*)embIb, NIi * 16);
    k_f2bf<<<nblk((long long)NAa * 16, B), B, 0, stream>>>((const float4*)emb_author,
                                                           (uint2*)embAb, NAa * 16);

    // ========== atom branch: 3-layer propagate on g0 ==========
    build_csr(g0r, g0c, g0v, E0, NN0, 9);
    k_spmm<0, true><<<nblk(NN0, 4), B, 0, stream>>>(rp, spair, embUb, embIb, NUu,
                                                    nullptr, nullptr, nullptr, nullptr,
                                                    nullptr, nullptr, nullptr,
                                                    y1b, nullptr, nullptr, NN0);
    k_spmm<0, false><<<nblk(NN0, 4), B, 0, stream>>>(rp, spair, y1b, nullptr, 0,
                                                     nullptr, nullptr, nullptr, nullptr,
                                                     nullptr, nullptr, nullptr,
                                                     y2b, nullptr, nullptr, NN0);
    k_spmm<1, false><<<nblk(NN0, 4), B, 0, stream>>>(rp, spair, y2b, nullptr, NUu,
                                                     emb_user, emb_item, y1b, y2b,
                                                     oUserA, items0, items0b,
                                                     nullptr, nullptr, nullptr, NN0);

    // ========== non-atom branch: 3-layer propagate on g1 ==========
    build_csr(g1r, g1c, g1v, E1, NN1, 9);
    k_spmm<0, true><<<nblk(NN1, 4), B, 0, stream>>>(rp, spair, embUb, embAb, NUu,
                                                    nullptr, nullptr, nullptr, nullptr,
                                                    nullptr, nullptr, nullptr,
                                                    y1b, nullptr, nullptr, NN1);
    k_spmm<0, false><<<nblk(NN1, 4), B, 0, stream>>>(rp, spair, y1b, nullptr, 0,
                                                     nullptr, nullptr, nullptr, nullptr,
                                                     nullptr, nullptr, nullptr,
                                                     y2b, nullptr, nullptr, NN1);
    k_spmm<1, false><<<nblk(NN1, 4), B, 0, stream>>>(rp, spair, y2b, nullptr, NUu,
                                                     emb_user, emb_author, y1b, y2b,
                                                     oUserN, oAuthN, oAuthNb,
                                                     nullptr, nullptr, nullptr, NN1);

    // ========== atom_authors = normalize(g3 @ items0) ==========
    build_csr(g3r, g3c, g3v, E3, NAa, 5);
    k_spmm<2, false><<<nblk(NAa, 4), B, 0, stream>>>(rp, spair, items0b, nullptr, 0,
                                                     nullptr, nullptr, nullptr, nullptr,
                                                     nullptr, nullptr, nullptr,
                                                     nullptr, oAuthA, nullptr, NAa);

    // ========== atom_items = 0.5*normalize(g5 @ items0) + 0.5*items0 ==========
    build_csr(g5r, g5c, g5v, E5, NIi, 8);
    k_spmm<3, false><<<nblk(NIi, 4), B, 0, stream>>>(rp, spair, items0b, nullptr, 0,
                                                     nullptr, nullptr, nullptr, nullptr,
                                                     nullptr, nullptr, nullptr,
                                                     nullptr, oItemA, items0, NIi);

    // ========== non_atom_items = normalize(g4 @ non_atom_authors) ==========
    build_csr(g4r, g4c, g4v, E4, NIi, 8);
    k_spmm<2, false><<<nblk(NIi, 4), B, 0, stream>>>(rp, spair, oAuthNb, nullptr, 0,
                                                     nullptr, nullptr, nullptr, nullptr,
                                                     nullptr, nullptr, nullptr,
                                                     nullptr, oItemN, nullptr, NIi);
}

// Round 9
// 1211.878 us; speedup vs baseline: 1.3186x; 1.1301x over previous
//
#include <hip/hip_runtime.h>

#define NUu 100000
#define NIi 100000
#define NAa 10000
#define DD  64
#define NN0 (NUu + NIi)   // 200000
#define NN1 (NUu + NAa)   // 110000

typedef unsigned int uint;

// ---------------- bf16 helpers ----------------

__device__ __forceinline__ uint pack_bf2(float x, float y) {
    uint a = __float_as_uint(x);
    uint b = __float_as_uint(y);
    a = (a + 0x7fffu + ((a >> 16) & 1u)) >> 16;          // RNE low half
    b = (b + 0x7fffu + ((b >> 16) & 1u)) & 0xffff0000u;  // RNE high half
    return (a & 0xffffu) | b;
}
__device__ __forceinline__ float bflo(uint w) { return __uint_as_float(w << 16); }
__device__ __forceinline__ float bfhi(uint w) { return __uint_as_float(w & 0xffff0000u); }

// convert fp32 -> packed bf16x2 (float4 -> uint2), n4 = nfloats/4
__global__ void k_f2bf(const float4* __restrict__ src, uint2* __restrict__ dst, int n4) {
    int i = blockIdx.x * blockDim.x + threadIdx.x;
    if (i >= n4) return;
    float4 v = src[i];
    uint2 o;
    o.x = pack_bf2(v.x, v.y);
    o.y = pack_bf2(v.z, v.w);
    dst[i] = o;
}

// ---------------- CSR build (bin-partition, no global row histogram) ----------------

#define P1_ITER 8
#define SEG_CAP 18944     // LDS-staged edges per bin in k_part2 (148KB)

// per-block LDS histogram over bins -> one global add per (block,bin)
__global__ void __launch_bounds__(1024)
k_binhist(const int* __restrict__ row, int* __restrict__ binCnt,
          int E, int shift, int nbins) {
    __shared__ int h[512];
    for (int t = threadIdx.x; t < nbins; t += blockDim.x) h[t] = 0;
    __syncthreads();
    int e0 = blockIdx.x * (blockDim.x * P1_ITER) + threadIdx.x;
#pragma unroll
    for (int i = 0; i < P1_ITER; ++i) {
        int e = e0 + i * blockDim.x;
        if (e < E) atomicAdd(&h[row[e] >> shift], 1);
    }
    __syncthreads();
    for (int t = threadIdx.x; t < nbins; t += blockDim.x)
        if (h[t]) atomicAdd(binCnt + t, h[t]);
}

// single-block exclusive scan of bin counts -> binBase (nbins+1), binCur
__global__ void k_binscan(const int* __restrict__ binCnt, int* __restrict__ binBase,
                          int* __restrict__ binCur, int nbins, int E) {
    __shared__ int s[512];
    int tid = threadIdx.x;
    int v = (tid < nbins) ? binCnt[tid] : 0;
    s[tid] = v;
    __syncthreads();
    for (int off = 1; off < 512; off <<= 1) {
        int t = (tid >= off) ? s[tid - off] : 0;
        __syncthreads();
        s[tid] += t;
        __syncthreads();
    }
    if (tid < nbins) {
        int b = s[tid] - v;
        binBase[tid] = b;
        binCur[tid] = b;
    }
    if (tid == 0) binBase[nbins] = E;
}

// P1: partition edges into per-bin staged segments; stage = {rowlow<<18 | col, val}
__global__ void __launch_bounds__(1024)
k_part1(const int* __restrict__ row, const int* __restrict__ col,
        const float* __restrict__ val, int* __restrict__ binCur,
        int2* __restrict__ stageP, int E, int shift, int nbins) {
    __shared__ int h[512];
    for (int t = threadIdx.x; t < nbins; t += blockDim.x) h[t] = 0;
    __syncthreads();
    int e0 = blockIdx.x * (blockDim.x * P1_ITER) + threadIdx.x;
    int r[P1_ITER];
#pragma unroll
    for (int i = 0; i < P1_ITER; ++i) {
        int e = e0 + i * blockDim.x;
        r[i] = (e < E) ? row[e] : -1;
        if (r[i] >= 0) atomicAdd(&h[r[i] >> shift], 1);
    }
    __syncthreads();
    for (int t = threadIdx.x; t < nbins; t += blockDim.x) {
        int c = h[t];
        h[t] = c ? atomicAdd(binCur + t, c) : 0;
    }
    __syncthreads();
#pragma unroll
    for (int i = 0; i < P1_ITER; ++i) {
        int e = e0 + i * blockDim.x;
        if (e < E) {
            int rr = r[i];
            int pos = atomicAdd(&h[rr >> shift], 1);
            int2 p;
            p.x = ((rr & ((1 << shift) - 1)) << 18) | col[e];
            p.y = __float_as_int(val[e]);
            stageP[pos] = p;
        }
    }
}

// P2: one block per bin. Stage bin segment in LDS once, count per-row, scan -> rp,
// then exact placement — reads stageP from global exactly once.
__global__ void __launch_bounds__(1024)
k_part2(const int* __restrict__ binBase, const int2* __restrict__ stageP,
        int2* __restrict__ spair, int* __restrict__ rp, int N, int shift) {
    __shared__ int2 seg[SEG_CAP];
    __shared__ int h[512];
    __shared__ int s[512];
    int tid = threadIdx.x;
    int rbase = blockIdx.x << shift;
    int nr = min(1 << shift, N - rbase);
    int es = binBase[blockIdx.x];
    int ee = binBase[blockIdx.x + 1];
    int n = ee - es;
    bool inLds = (n <= SEG_CAP);
    if (tid < 512) h[tid] = 0;
    if (inLds)
        for (int i = tid; i < n; i += blockDim.x) seg[i] = stageP[es + i];
    __syncthreads();
    if (inLds) {
        for (int i = tid; i < n; i += blockDim.x)
            atomicAdd(&h[seg[i].x >> 18], 1);
    } else {
        for (int i = es + tid; i < ee; i += blockDim.x)
            atomicAdd(&h[stageP[i].x >> 18], 1);
    }
    __syncthreads();
    int v = (tid < 512) ? h[tid] : 0;
    if (tid < 512) s[tid] = v;
    __syncthreads();
    for (int off = 1; off < 512; off <<= 1) {
        int t = (tid < 512 && tid >= off) ? s[tid - off] : 0;
        __syncthreads();
        if (tid < 512) s[tid] += t;
        __syncthreads();
    }
    if (tid < 512) h[tid] = es + s[tid] - v;   // row cursor
    if (tid < nr) rp[rbase + tid] = es + s[tid] - v;
    if (tid == 0 && rbase + nr == N) rp[N] = ee;
    __syncthreads();
    if (inLds) {
        for (int i = tid; i < n; i += blockDim.x) {
            int2 p = seg[i];
            int pos = atomicAdd(&h[p.x >> 18], 1);
            int2 o;
            o.x = p.x & 0x3ffff;
            o.y = p.y;
            spair[pos] = o;
        }
    } else {
        for (int i = es + tid; i < ee; i += blockDim.x) {
            int2 p = stageP[i];
            int pos = atomicAdd(&h[p.x >> 18], 1);
            int2 o;
            o.x = p.x & 0x3ffff;
            o.y = p.y;
            spair[pos] = o;
        }
    }
}

// ---------------- SpMM (bf16 gather, one wave = one row, quarter-wave/edge) ----------------
// lane = q*16 + d8 : quarter q owns one edge slot; lane reads uint2 = dims 4*d8 .. 4*d8+3.
// Main loop: 16 edges/iter = 4 spair loads + 4 uint2-gathers (2KB/wave in flight).

template <bool SS>
__device__ __forceinline__ const uint* gb(long long q, const uint* xbA, const uint* xbB,
                                          int split) {
    int c = (int)q;
    if (SS) return (c < split) ? xbA + (((long long)c) << 5)
                               : xbB + (((long long)(c - split)) << 5);
    return xbA + (((long long)c) << 5);
}

// MODE 0: plain  — ob = pack(a)
// MODE 1: final  — out = 0.25*(emb + y1 + y2 + a); fp32 out split U/I, optional bf16 outIb
// MODE 2: norm   — yf = normalize(a)
// MODE 3: blend  — yf = 0.5*normalize(a) + 0.5*base
template <int MODE, bool SS>
__global__ void k_spmm(const int* __restrict__ rp, const int2* __restrict__ sp,
                       const uint* __restrict__ xbA, const uint* __restrict__ xbB, int split,
                       const float* __restrict__ embA, const float* __restrict__ embB,
                       const uint* __restrict__ y1b, const uint* __restrict__ y2b,
                       float* __restrict__ outU, float* __restrict__ outI,
                       uint* __restrict__ outIb,
                       uint* __restrict__ ob, float* __restrict__ yf,
                       const float* __restrict__ base, int nrows) {
    int r = blockIdx.x * (blockDim.x >> 6) + (threadIdx.x >> 6);
    if (r >= nrows) return;
    int lane = threadIdx.x & 63;
    int q = lane >> 4;        // edge slot within group of 4
    int d8 = lane & 15;       // covers dims 4*d8 .. 4*d8+3

    int s0 = rp[r], e0 = rp[r + 1];
    float a0 = 0.f, a1 = 0.f, a2 = 0.f, a3 = 0.f;
    int i = s0;
    for (; i + 16 <= e0; i += 16) {
        long long e0v = *(const long long*)(sp + i + q);
        long long e1v = *(const long long*)(sp + i + 4 + q);
        long long e2v = *(const long long*)(sp + i + 8 + q);
        long long e3v = *(const long long*)(sp + i + 12 + q);
        uint2 w0 = *(const uint2*)(gb<SS>(e0v, xbA, xbB, split) + 2 * d8);
        uint2 w1 = *(const uint2*)(gb<SS>(e1v, xbA, xbB, split) + 2 * d8);
        uint2 w2 = *(const uint2*)(gb<SS>(e2v, xbA, xbB, split) + 2 * d8);
        uint2 w3 = *(const uint2*)(gb<SS>(e3v, xbA, xbB, split) + 2 * d8);
        float v0 = __int_as_float((int)(e0v >> 32));
        float v1 = __int_as_float((int)(e1v >> 32));
        float v2 = __int_as_float((int)(e2v >> 32));
        float v3 = __int_as_float((int)(e3v >> 32));
        a0 += v0 * bflo(w0.x); a1 += v0 * bfhi(w0.x); a2 += v0 * bflo(w0.y); a3 += v0 * bfhi(w0.y);
        a0 += v1 * bflo(w1.x); a1 += v1 * bfhi(w1.x); a2 += v1 * bflo(w1.y); a3 += v1 * bfhi(w1.y);
        a0 += v2 * bflo(w2.x); a1 += v2 * bfhi(w2.x); a2 += v2 * bflo(w2.y); a3 += v2 * bfhi(w2.y);
        a0 += v3 * bflo(w3.x); a1 += v3 * bfhi(w3.x); a2 += v3 * bflo(w3.y); a3 += v3 * bfhi(w3.y);
    }
    for (; i < e0; i += 4) {
        int idx = i + q;
        long long ev = 0;                       // col 0, val 0 pad
        if (idx < e0) ev = *(const long long*)(sp + idx);
        uint2 wv = *(const uint2*)(gb<SS>(ev, xbA, xbB, split) + 2 * d8);
        float v = __int_as_float((int)(ev >> 32));
        a0 += v * bflo(wv.x); a1 += v * bfhi(wv.x); a2 += v * bflo(wv.y); a3 += v * bfhi(wv.y);
    }
    // reduce across the 4 quarters (lanes with equal d8)
    a0 += __shfl_xor(a0, 16); a0 += __shfl_xor(a0, 32);
    a1 += __shfl_xor(a1, 16); a1 += __shfl_xor(a1, 32);
    a2 += __shfl_xor(a2, 16); a2 += __shfl_xor(a2, 32);
    a3 += __shfl_xor(a3, 16); a3 += __shfl_xor(a3, 32);

    long long off4 = (((long long)r) << 6) + 4 * d8;     // float index of dim 4*d8
    long long offw = (((long long)r) << 5) + 2 * d8;     // uint index

    if (MODE == 0) {
        if (q == 0) {
            uint2 o;
            o.x = pack_bf2(a0, a1);
            o.y = pack_bf2(a2, a3);
            *(uint2*)(ob + offw) = o;
        }
    } else if (MODE == 1) {
        if (q == 0) {
            float4 e4;
            if (r < split) e4 = *(const float4*)(embA + off4);
            else           e4 = *(const float4*)(embB + (off4 - (((long long)split) << 6)));
            uint2 w1 = *(const uint2*)(y1b + offw);
            uint2 w2 = *(const uint2*)(y2b + offw);
            float s0f = 0.25f * (e4.x + bflo(w1.x) + bflo(w2.x) + a0);
            float s1f = 0.25f * (e4.y + bfhi(w1.x) + bfhi(w2.x) + a1);
            float s2f = 0.25f * (e4.z + bflo(w1.y) + bflo(w2.y) + a2);
            float s3f = 0.25f * (e4.w + bfhi(w1.y) + bfhi(w2.y) + a3);
            float4 o;
            o.x = s0f; o.y = s1f; o.z = s2f; o.w = s3f;
            if (r < split) {
                *(float4*)(outU + off4) = o;
            } else {
                *(float4*)(outI + (off4 - (((long long)split) << 6))) = o;
                if (outIb) {
                    uint2 ob2;
                    ob2.x = pack_bf2(s0f, s1f);
                    ob2.y = pack_bf2(s2f, s3f);
                    *(uint2*)(outIb + (((long long)(r - split)) << 5) + 2 * d8) = ob2;
                }
            }
        }
    } else {
        float sq = a0 * a0 + a1 * a1 + a2 * a2 + a3 * a3;
        sq += __shfl_xor(sq, 1); sq += __shfl_xor(sq, 2);
        sq += __shfl_xor(sq, 4); sq += __shfl_xor(sq, 8);
        float inv = 1.0f / fmaxf(sqrtf(sq), 1e-12f);
        if (q == 0) {
            float4 o;
            if (MODE == 2) {
                o.x = a0 * inv; o.y = a1 * inv; o.z = a2 * inv; o.w = a3 * inv;
            } else {
                float4 b4 = *(const float4*)(base + off4);
                o.x = 0.5f * a0 * inv + 0.5f * b4.x;
                o.y = 0.5f * a1 * inv + 0.5f * b4.y;
                o.z = 0.5f * a2 * inv + 0.5f * b4.z;
                o.w = 0.5f * a3 * inv + 0.5f * b4.w;
            }
            *(float4*)(yf + off4) = o;
        }
    }
}

// ---------------- host ----------------

static inline int nblk(long long n, int b) { return (int)((n + b - 1) / b); }
static inline size_t al256(size_t x) { return (x + 255) & ~(size_t)255; }

extern "C" void kernel_launch(void* const* d_in, const int* in_sizes, int n_in,
                              void* d_out, int out_size, void* d_ws, size_t ws_size,
                              hipStream_t stream) {
    const float* emb_user   = (const float*)d_in[0];
    const float* emb_item   = (const float*)d_in[1];
    const float* emb_author = (const float*)d_in[2];
    const int*   g0r = (const int*)d_in[3];
    const int*   g0c = (const int*)d_in[4];
    const float* g0v = (const float*)d_in[5];
    const int*   g1r = (const int*)d_in[6];
    const int*   g1c = (const int*)d_in[7];
    const float* g1v = (const float*)d_in[8];
    const int*   g3r = (const int*)d_in[9];
    const int*   g3c = (const int*)d_in[10];
    const float* g3v = (const float*)d_in[11];
    const int*   g4r = (const int*)d_in[12];
    const int*   g4c = (const int*)d_in[13];
    const float* g4v = (const float*)d_in[14];
    const int*   g5r = (const int*)d_in[15];
    const int*   g5c = (const int*)d_in[16];
    const float* g5v = (const float*)d_in[17];

    const int E0 = in_sizes[3];
    const int E1 = in_sizes[6];
    const int E3 = in_sizes[9];
    const int E4 = in_sizes[12];
    const int E5 = in_sizes[15];

    float* out = (float*)d_out;

    // ---- workspace carve-up ----
    char* w = (char*)d_ws;
    int*  rp      = (int*)w;  w += al256((size_t)(NN0 + 1) * 4);
    int*  binCnt  = (int*)w;  w += al256((size_t)512 * 4);
    int*  binBase = (int*)w;  w += al256((size_t)513 * 4);
    int*  binCur  = (int*)w;  w += al256((size_t)512 * 4);
    int2* spair   = (int2*)w; w += al256((size_t)6400000 * 8);
    uint* embUb   = (uint*)w; w += al256((size_t)NUu * 32 * 4);   // bf16 embeddings
    uint* embIb   = (uint*)w; w += al256((size_t)NIi * 32 * 4);
    uint* embAb   = (uint*)w; w += al256((size_t)NAa * 32 * 4);
    uint* y1b     = (uint*)w; w += al256((size_t)NN0 * 32 * 4);   // bf16 layer outs
    uint* y2b     = (uint*)w; w += al256((size_t)NN0 * 32 * 4);
    float* items0  = (float*)w; w += al256((size_t)NIi * DD * 4); // fp32 atom_items0
    uint*  items0b = (uint*)w;  w += al256((size_t)NIi * 32 * 4); // bf16 atom_items0
    uint*  oAuthNb = (uint*)w;  w += al256((size_t)NAa * 32 * 4); // bf16 non_atom_authors
    // staging aliases y1b+y2b (dead during builds): E*8 <= 51.2MB
    int2* stageP = (int2*)y1b;

    const int B = 256;

    auto build_csr = [&](const int* row, const int* col, const float* val,
                         int E, int N, int shift) {
        int nbins = (N + (1 << shift) - 1) >> shift;
        hipMemsetAsync(binCnt, 0, (size_t)nbins * sizeof(int), stream);
        k_binhist<<<nblk(E, 1024 * P1_ITER), 1024, 0, stream>>>(row, binCnt, E, shift, nbins);
        k_binscan<<<1, 512, 0, stream>>>(binCnt, binBase, binCur, nbins, E);
        k_part1<<<nblk(E, 1024 * P1_ITER), 1024, 0, stream>>>(row, col, val, binCur,
                                                              stageP, E, shift, nbins);
        k_part2<<<nbins, 1024, 0, stream>>>(binBase, stageP, spair, rp, N, shift);
    };

    float* oUserA = out;                            // atom_users
    float* oUserN = out + (long long)NUu * DD;      // non_atom_users
    float* oItemA = out + (long long)200000 * DD;   // atom_items
    float* oItemN = out + (long long)300000 * DD;   // non_atom_items
    float* oAuthA = out + (long long)400000 * DD;   // atom_authors
    float* oAuthN = out + (long long)410000 * DD;   // non_atom_authors

    // ---- convert all embeddings to bf16 once ----
    k_f2bf<<<nblk((long long)NUu * 16, B), B, 0, stream>>>((const float4*)emb_user,
                                                           (uint2*)embUb, NUu * 16);
    k_f2bf<<<nblk((long long)NIi * 16, B), B, 0, stream>>>((const float4*)emb_item,
                                                           (uint2*)embIb, NIi * 16);
    k_f2bf<<<nblk((long long)NAa * 16, B), B, 0, stream>>>((const float4*)emb_author,
                                                           (uint2*)embAb, NAa * 16);

    // ========== atom branch: 3-layer propagate on g0 ==========
    build_csr(g0r, g0c, g0v, E0, NN0, 9);
    k_spmm<0, true><<<nblk(NN0, 4), B, 0, stream>>>(rp, spair, embUb, embIb, NUu,
                                                    nullptr, nullptr, nullptr, nullptr,
                                                    nullptr, nullptr, nullptr,
                                                    y1b, nullptr, nullptr, NN0);
    k_spmm<0, false><<<nblk(NN0, 4), B, 0, stream>>>(rp, spair, y1b, nullptr, 0,
                                                     nullptr, nullptr, nullptr, nullptr,
                                                     nullptr, nullptr, nullptr,
                                                     y2b, nullptr, nullptr, NN0);
    k_spmm<1, false><<<nblk(NN0, 4), B, 0, stream>>>(rp, spair, y2b, nullptr, NUu,
                                                     emb_user, emb_item, y1b, y2b,
                                                     oUserA, items0, items0b,
                                                     nullptr, nullptr, nullptr, NN0);

    // ========== non-atom branch: 3-layer propagate on g1 ==========
    build_csr(g1r, g1c, g1v, E1, NN1, 9);
    k_spmm<0, true><<<nblk(NN1, 4), B, 0, stream>>>(rp, spair, embUb, embAb, NUu,
                                                    nullptr, nullptr, nullptr, nullptr,
                                                    nullptr, nullptr, nullptr,
                                                    y1b, nullptr, nullptr, NN1);
    k_spmm<0, false><<<nblk(NN1, 4), B, 0, stream>>>(rp, spair, y1b, nullptr, 0,
                                                     nullptr, nullptr, nullptr, nullptr,
                                                     nullptr, nullptr, nullptr,
                                                     y2b, nullptr, nullptr, NN1);
    k_spmm<1, false><<<nblk(NN1, 4), B, 0, stream>>>(rp, spair, y2b, nullptr, NUu,
                                                     emb_user, emb_author, y1b, y2b,
                                                     oUserN, oAuthN, oAuthNb,
                                                     nullptr, nullptr, nullptr, NN1);

    // ========== atom_authors = normalize(g3 @ items0) ==========
    build_csr(g3r, g3c, g3v, E3, NAa, 5);
    k_spmm<2, false><<<nblk(NAa, 4), B, 0, stream>>>(rp, spair, items0b, nullptr, 0,
                                                     nullptr, nullptr, nullptr, nullptr,
                                                     nullptr, nullptr, nullptr,
                                                     nullptr, oAuthA, nullptr, NAa);

    // ========== atom_items = 0.5*normalize(g5 @ items0) + 0.5*items0 ==========
    build_csr(g5r, g5c, g5v, E5, NIi, 8);
    k_spmm<3, false><<<nblk(NIi, 4), B, 0, stream>>>(rp, spair, items0b, nullptr, 0,
                                                     nullptr, nullptr, nullptr, nullptr,
                                                     nullptr, nullptr, nullptr,
                                                     nullptr, oItemA, items0, NIi);

    // ========== non_atom_items = normalize(g4 @ non_atom_authors) ==========
    build_csr(g4r, g4c, g4v, E4, NIi, 8);
    k_spmm<2, false><<<nblk(NIi, 4), B, 0, stream>>>(rp, spair, oAuthNb, nullptr, 0,
                                                     nullptr, nullptr, nullptr, nullptr,
                                                     nullptr, nullptr, nullptr,
                                                     nullptr, oItemN, nullptr, NIi);
}

// Round 10
// 1196.171 us; speedup vs baseline: 1.3359x; 1.0131x over previous
//
#include <hip/hip_runtime.h>

#define NUu 100000
#define NIi 100000
#define NAa 10000
#define DD  64
#define NN0 (NUu + NIi)   // 200000
#define NN1 (NUu + NAa)   // 110000

typedef unsigned int uint;

// ---------------- bf16 helpers ----------------

__device__ __forceinline__ uint pack_bf2(float x, float y) {
    uint a = __float_as_uint(x);
    uint b = __float_as_uint(y);
    a = (a + 0x7fffu + ((a >> 16) & 1u)) >> 16;          // RNE low half
    b = (b + 0x7fffu + ((b >> 16) & 1u)) & 0xffff0000u;  // RNE high half
    return (a & 0xffffu) | b;
}
__device__ __forceinline__ float bflo(uint w) { return __uint_as_float(w << 16); }
__device__ __forceinline__ float bfhi(uint w) { return __uint_as_float(w & 0xffff0000u); }

// convert fp32 -> packed bf16x2 (float4 -> uint2), n4 = nfloats/4
__global__ void k_f2bf(const float4* __restrict__ src, uint2* __restrict__ dst, int n4) {
    int i = blockIdx.x * blockDim.x + threadIdx.x;
    if (i >= n4) return;
    float4 v = src[i];
    uint2 o;
    o.x = pack_bf2(v.x, v.y);
    o.y = pack_bf2(v.z, v.w);
    dst[i] = o;
}

// ---------------- CSR build (bin-partition, no global row histogram) ----------------

#define P1_ITER 8
#define SEG_CAP 18944     // LDS-staged edges per bin in k_part2 (148KB)

// per-block LDS histogram over bins -> one global add per (block,bin)
__global__ void __launch_bounds__(1024)
k_binhist(const int* __restrict__ row, int* __restrict__ binCnt,
          int E, int shift, int nbins) {
    __shared__ int h[512];
    for (int t = threadIdx.x; t < nbins; t += blockDim.x) h[t] = 0;
    __syncthreads();
    int e0 = blockIdx.x * (blockDim.x * P1_ITER) + threadIdx.x;
#pragma unroll
    for (int i = 0; i < P1_ITER; ++i) {
        int e = e0 + i * blockDim.x;
        if (e < E) atomicAdd(&h[row[e] >> shift], 1);
    }
    __syncthreads();
    for (int t = threadIdx.x; t < nbins; t += blockDim.x)
        if (h[t]) atomicAdd(binCnt + t, h[t]);
}

// single-block exclusive scan of bin counts -> binBase (nbins+1), binCur
__global__ void k_binscan(const int* __restrict__ binCnt, int* __restrict__ binBase,
                          int* __restrict__ binCur, int nbins, int E) {
    __shared__ int s[512];
    int tid = threadIdx.x;
    int v = (tid < nbins) ? binCnt[tid] : 0;
    s[tid] = v;
    __syncthreads();
    for (int off = 1; off < 512; off <<= 1) {
        int t = (tid >= off) ? s[tid - off] : 0;
        __syncthreads();
        s[tid] += t;
        __syncthreads();
    }
    if (tid < nbins) {
        int b = s[tid] - v;
        binBase[tid] = b;
        binCur[tid] = b;
    }
    if (tid == 0) binBase[nbins] = E;
}

// P1: partition edges into per-bin staged segments; stage = {rowlow<<18 | col, val}
__global__ void __launch_bounds__(1024)
k_part1(const int* __restrict__ row, const int* __restrict__ col,
        const float* __restrict__ val, int* __restrict__ binCur,
        int2* __restrict__ stageP, int E, int shift, int nbins) {
    __shared__ int h[512];
    for (int t = threadIdx.x; t < nbins; t += blockDim.x) h[t] = 0;
    __syncthreads();
    int e0 = blockIdx.x * (blockDim.x * P1_ITER) + threadIdx.x;
    int r[P1_ITER];
#pragma unroll
    for (int i = 0; i < P1_ITER; ++i) {
        int e = e0 + i * blockDim.x;
        r[i] = (e < E) ? row[e] : -1;
        if (r[i] >= 0) atomicAdd(&h[r[i] >> shift], 1);
    }
    __syncthreads();
    for (int t = threadIdx.x; t < nbins; t += blockDim.x) {
        int c = h[t];
        h[t] = c ? atomicAdd(binCur + t, c) : 0;
    }
    __syncthreads();
#pragma unroll
    for (int i = 0; i < P1_ITER; ++i) {
        int e = e0 + i * blockDim.x;
        if (e < E) {
            int rr = r[i];
            int pos = atomicAdd(&h[rr >> shift], 1);
            int2 p;
            p.x = ((rr & ((1 << shift) - 1)) << 18) | col[e];
            p.y = __float_as_int(val[e]);
            stageP[pos] = p;
        }
    }
}

// P2: one block per bin. Stage bin segment in LDS once, count per-row, scan -> rp,
// then exact placement — reads stageP from global exactly once.
__global__ void __launch_bounds__(1024)
k_part2(const int* __restrict__ binBase, const int2* __restrict__ stageP,
        int2* __restrict__ spair, int* __restrict__ rp, int N, int shift) {
    __shared__ int2 seg[SEG_CAP];
    __shared__ int h[512];
    __shared__ int s[512];
    int tid = threadIdx.x;
    int rbase = blockIdx.x << shift;
    int nr = min(1 << shift, N - rbase);
    int es = binBase[blockIdx.x];
    int ee = binBase[blockIdx.x + 1];
    int n = ee - es;
    bool inLds = (n <= SEG_CAP);
    if (tid < 512) h[tid] = 0;
    if (inLds)
        for (int i = tid; i < n; i += blockDim.x) seg[i] = stageP[es + i];
    __syncthreads();
    if (inLds) {
        for (int i = tid; i < n; i += blockDim.x)
            atomicAdd(&h[seg[i].x >> 18], 1);
    } else {
        for (int i = es + tid; i < ee; i += blockDim.x)
            atomicAdd(&h[stageP[i].x >> 18], 1);
    }
    __syncthreads();
    int v = (tid < 512) ? h[tid] : 0;
    if (tid < 512) s[tid] = v;
    __syncthreads();
    for (int off = 1; off < 512; off <<= 1) {
        int t = (tid < 512 && tid >= off) ? s[tid - off] : 0;
        __syncthreads();
        if (tid < 512) s[tid] += t;
        __syncthreads();
    }
    if (tid < 512) h[tid] = es + s[tid] - v;   // row cursor
    if (tid < nr) rp[rbase + tid] = es + s[tid] - v;
    if (tid == 0 && rbase + nr == N) rp[N] = ee;
    __syncthreads();
    if (inLds) {
        for (int i = tid; i < n; i += blockDim.x) {
            int2 p = seg[i];
            int pos = atomicAdd(&h[p.x >> 18], 1);
            int2 o;
            o.x = p.x & 0x3ffff;
            o.y = p.y;
            spair[pos] = o;
        }
    } else {
        for (int i = es + tid; i < ee; i += blockDim.x) {
            int2 p = stageP[i];
            int pos = atomicAdd(&h[p.x >> 18], 1);
            int2 o;
            o.x = p.x & 0x3ffff;
            o.y = p.y;
            spair[pos] = o;
        }
    }
}

// ---------------- SpMM (bf16 gather, one wave = one row, quarter-wave/edge) ----------------
// lane = q*16 + d8 : quarter q owns one edge slot; lane reads uint2 = dims 4*d8 .. 4*d8+3.
// Main loop: 32 edges/iter = 8 spair loads + 8 uint2-gathers (4KB/wave in flight).

template <bool SS>
__device__ __forceinline__ const uint* gb(long long q, const uint* xbA, const uint* xbB,
                                          int split) {
    int c = (int)q;
    if (SS) return (c < split) ? xbA + (((long long)c) << 5)
                               : xbB + (((long long)(c - split)) << 5);
    return xbA + (((long long)c) << 5);
}

// MODE 0: plain  — ob = pack(a)
// MODE 1: final  — out = 0.25*(emb + y1 + y2 + a); fp32 out split U/I, optional bf16 outIb
// MODE 2: norm   — yf = normalize(a)
// MODE 3: blend  — yf = 0.5*normalize(a) + 0.5*base
template <int MODE, bool SS>
__global__ void k_spmm(const int* __restrict__ rp, const int2* __restrict__ sp,
                       const uint* __restrict__ xbA, const uint* __restrict__ xbB, int split,
                       const float* __restrict__ embA, const float* __restrict__ embB,
                       const uint* __restrict__ y1b, const uint* __restrict__ y2b,
                       float* __restrict__ outU, float* __restrict__ outI,
                       uint* __restrict__ outIb,
                       uint* __restrict__ ob, float* __restrict__ yf,
                       const float* __restrict__ base, int nrows) {
    int r = blockIdx.x * (blockDim.x >> 6) + (threadIdx.x >> 6);
    if (r >= nrows) return;
    int lane = threadIdx.x & 63;
    int q = lane >> 4;        // edge slot within group of 4
    int d8 = lane & 15;       // covers dims 4*d8 .. 4*d8+3

    int s0 = rp[r], e0 = rp[r + 1];
    float a0 = 0.f, a1 = 0.f, a2 = 0.f, a3 = 0.f;
    int i = s0;
    for (; i + 32 <= e0; i += 32) {
        long long ev[8];
#pragma unroll
        for (int s = 0; s < 8; ++s)
            ev[s] = *(const long long*)(sp + i + 4 * s + q);
        uint2 wv[8];
#pragma unroll
        for (int s = 0; s < 8; ++s)
            wv[s] = *(const uint2*)(gb<SS>(ev[s], xbA, xbB, split) + 2 * d8);
#pragma unroll
        for (int s = 0; s < 8; ++s) {
            float v = __int_as_float((int)(ev[s] >> 32));
            a0 += v * bflo(wv[s].x); a1 += v * bfhi(wv[s].x);
            a2 += v * bflo(wv[s].y); a3 += v * bfhi(wv[s].y);
        }
    }
    for (; i + 8 <= e0; i += 8) {
        long long e0v = *(const long long*)(sp + i + q);
        long long e1v = *(const long long*)(sp + i + 4 + q);
        uint2 w0 = *(const uint2*)(gb<SS>(e0v, xbA, xbB, split) + 2 * d8);
        uint2 w1 = *(const uint2*)(gb<SS>(e1v, xbA, xbB, split) + 2 * d8);
        float v0 = __int_as_float((int)(e0v >> 32));
        float v1 = __int_as_float((int)(e1v >> 32));
        a0 += v0 * bflo(w0.x); a1 += v0 * bfhi(w0.x);
        a2 += v0 * bflo(w0.y); a3 += v0 * bfhi(w0.y);
        a0 += v1 * bflo(w1.x); a1 += v1 * bfhi(w1.x);
        a2 += v1 * bflo(w1.y); a3 += v1 * bfhi(w1.y);
    }
    for (; i < e0; i += 4) {
        int idx = i + q;
        long long ev = 0;                       // col 0, val 0 pad
        if (idx < e0) ev = *(const long long*)(sp + idx);
        uint2 wv = *(const uint2*)(gb<SS>(ev, xbA, xbB, split) + 2 * d8);
        float v = __int_as_float((int)(ev >> 32));
        a0 += v * bflo(wv.x); a1 += v * bfhi(wv.x); a2 += v * bflo(wv.y); a3 += v * bfhi(wv.y);
    }
    // reduce across the 4 quarters (lanes with equal d8)
    a0 += __shfl_xor(a0, 16); a0 += __shfl_xor(a0, 32);
    a1 += __shfl_xor(a1, 16); a1 += __shfl_xor(a1, 32);
    a2 += __shfl_xor(a2, 16); a2 += __shfl_xor(a2, 32);
    a3 += __shfl_xor(a3, 16); a3 += __shfl_xor(a3, 32);

    long long off4 = (((long long)r) << 6) + 4 * d8;     // float index of dim 4*d8
    long long offw = (((long long)r) << 5) + 2 * d8;     // uint index

    if (MODE == 0) {
        if (q == 0) {
            uint2 o;
            o.x = pack_bf2(a0, a1);
            o.y = pack_bf2(a2, a3);
            *(uint2*)(ob + offw) = o;
        }
    } else if (MODE == 1) {
        if (q == 0) {
            float4 e4;
            if (r < split) e4 = *(const float4*)(embA + off4);
            else           e4 = *(const float4*)(embB + (off4 - (((long long)split) << 6)));
            uint2 w1 = *(const uint2*)(y1b + offw);
            uint2 w2 = *(const uint2*)(y2b + offw);
            float s0f = 0.25f * (e4.x + bflo(w1.x) + bflo(w2.x) + a0);
            float s1f = 0.25f * (e4.y + bfhi(w1.x) + bfhi(w2.x) + a1);
            float s2f = 0.25f * (e4.z + bflo(w1.y) + bflo(w2.y) + a2);
            float s3f = 0.25f * (e4.w + bfhi(w1.y) + bfhi(w2.y) + a3);
            float4 o;
            o.x = s0f; o.y = s1f; o.z = s2f; o.w = s3f;
            if (r < split) {
                *(float4*)(outU + off4) = o;
            } else {
                *(float4*)(outI + (off4 - (((long long)split) << 6))) = o;
                if (outIb) {
                    uint2 ob2;
                    ob2.x = pack_bf2(s0f, s1f);
                    ob2.y = pack_bf2(s2f, s3f);
                    *(uint2*)(outIb + (((long long)(r - split)) << 5) + 2 * d8) = ob2;
                }
            }
        }
    } else {
        float sq = a0 * a0 + a1 * a1 + a2 * a2 + a3 * a3;
        sq += __shfl_xor(sq, 1); sq += __shfl_xor(sq, 2);
        sq += __shfl_xor(sq, 4); sq += __shfl_xor(sq, 8);
        float inv = 1.0f / fmaxf(sqrtf(sq), 1e-12f);
        if (q == 0) {
            float4 o;
            if (MODE == 2) {
                o.x = a0 * inv; o.y = a1 * inv; o.z = a2 * inv; o.w = a3 * inv;
            } else {
                float4 b4 = *(const float4*)(base + off4);
                o.x = 0.5f * a0 * inv + 0.5f * b4.x;
                o.y = 0.5f * a1 * inv + 0.5f * b4.y;
                o.z = 0.5f * a2 * inv + 0.5f * b4.z;
                o.w = 0.5f * a3 * inv + 0.5f * b4.w;
            }
            *(float4*)(yf + off4) = o;
        }
    }
}

// ---------------- host ----------------

static inline int nblk(long long n, int b) { return (int)((n + b - 1) / b); }
static inline size_t al256(size_t x) { return (x + 255) & ~(size_t)255; }

extern "C" void kernel_launch(void* const* d_in, const int* in_sizes, int n_in,
                              void* d_out, int out_size, void* d_ws, size_t ws_size,
                              hipStream_t stream) {
    const float* emb_user   = (const float*)d_in[0];
    const float* emb_item   = (const float*)d_in[1];
    const float* emb_author = (const float*)d_in[2];
    const int*   g0r = (const int*)d_in[3];
    const int*   g0c = (const int*)d_in[4];
    const float* g0v = (const float*)d_in[5];
    const int*   g1r = (const int*)d_in[6];
    const int*   g1c = (const int*)d_in[7];
    const float* g1v = (const float*)d_in[8];
    const int*   g3r = (const int*)d_in[9];
    const int*   g3c = (const int*)d_in[10];
    const float* g3v = (const float*)d_in[11];
    const int*   g4r = (const int*)d_in[12];
    const int*   g4c = (const int*)d_in[13];
    const float* g4v = (const float*)d_in[14];
    const int*   g5r = (const int*)d_in[15];
    const int*   g5c = (const int*)d_in[16];
    const float* g5v = (const float*)d_in[17];

    const int E0 = in_sizes[3];
    const int E1 = in_sizes[6];
    const int E3 = in_sizes[9];
    const int E4 = in_sizes[12];
    const int E5 = in_sizes[15];

    float* out = (float*)d_out;

    // ---- workspace carve-up ----
    char* w = (char*)d_ws;
    int*  rp      = (int*)w;  w += al256((size_t)(NN0 + 1) * 4);
    int*  binCnt  = (int*)w;  w += al256((size_t)512 * 4);
    int*  binBase = (int*)w;  w += al256((size_t)513 * 4);
    int*  binCur  = (int*)w;  w += al256((size_t)512 * 4);
    int2* spair   = (int2*)w; w += al256((size_t)6400000 * 8);
    uint* embUb   = (uint*)w; w += al256((size_t)NUu * 32 * 4);   // bf16 embeddings
    uint* embIb   = (uint*)w; w += al256((size_t)NIi * 32 * 4);
    uint* embAb   = (uint*)w; w += al256((size_t)NAa * 32 * 4);
    uint* y1b     = (uint*)w; w += al256((size_t)NN0 * 32 * 4);   // bf16 layer outs
    uint* y2b     = (uint*)w; w += al256((size_t)NN0 * 32 * 4);
    float* items0  = (float*)w; w += al256((size_t)NIi * DD * 4); // fp32 atom_items0
    uint*  items0b = (uint*)w;  w += al256((size_t)NIi * 32 * 4); // bf16 atom_items0
    uint*  oAuthNb = (uint*)w;  w += al256((size_t)NAa * 32 * 4); // bf16 non_atom_authors
    // staging aliases y1b+y2b (dead during builds): E*8 <= 51.2MB
    int2* stageP = (int2*)y1b;

    const int B = 256;

    auto build_csr = [&](const int* row, const int* col, const float* val,
                         int E, int N, int shift) {
        int nbins = (N + (1 << shift) - 1) >> shift;
        hipMemsetAsync(binCnt, 0, (size_t)nbins * sizeof(int), stream);
        k_binhist<<<nblk(E, 1024 * P1_ITER), 1024, 0, stream>>>(row, binCnt, E, shift, nbins);
        k_binscan<<<1, 512, 0, stream>>>(binCnt, binBase, binCur, nbins, E);
        k_part1<<<nblk(E, 1024 * P1_ITER), 1024, 0, stream>>>(row, col, val, binCur,
                                                              stageP, E, shift, nbins);
        k_part2<<<nbins, 1024, 0, stream>>>(binBase, stageP, spair, rp, N, shift);
    };

    float* oUserA = out;                            // atom_users
    float* oUserN = out + (long long)NUu * DD;      // non_atom_users
    float* oItemA = out + (long long)200000 * DD;   // atom_items
    float* oItemN = out + (long long)300000 * DD;   // non_atom_items
    float* oAuthA = out + (long long)400000 * DD;   // atom_authors
    float* oAuthN = out + (long long)410000 * DD;   // non_atom_authors

    // ---- convert all embeddings to bf16 once ----
    k_f2bf<<<nblk((long long)NUu * 16, B), B, 0, stream>>>((const float4*)emb_user,
                                                           (uint2*)embUb, NUu * 16);
    k_f2bf<<<nblk((long long)NIi * 16, B), B, 0, stream>>>((const float4*)emb_item,
                                                           (uint2*)embIb, NIi * 16);
    k_f2bf<<<nblk((long long)NAa * 16, B), B, 0, stream>>>((const float4*)emb_author,
                                                           (uint2*)embAb, NAa * 16);

    // ========== atom branch: 3-layer propagate on g0 ==========
    build_csr(g0r, g0c, g0v, E0, NN0, 9);
    k_spmm<0, true><<<nblk(NN0, 4), B, 0, stream>>>(rp, spair, embUb, embIb, NUu,
                                                    nullptr, nullptr, nullptr, nullptr,
                                                    nullptr, nullptr, nullptr,
                                                    y1b, nullptr, nullptr, NN0);
    k_spmm<0, false><<<nblk(NN0, 4), B, 0, stream>>>(rp, spair, y1b, nullptr, 0,
                                                     nullptr, nullptr, nullptr, nullptr,
                                                     nullptr, nullptr, nullptr,
                                                     y2b, nullptr, nullptr, NN0);
    k_spmm<1, false><<<nblk(NN0, 4), B, 0, stream>>>(rp, spair, y2b, nullptr, NUu,
                                                     emb_user, emb_item, y1b, y2b,
                                                     oUserA, items0, items0b,
                                                     nullptr, nullptr, nullptr, NN0);

    // ========== non-atom branch: 3-layer propagate on g1 ==========
    build_csr(g1r, g1c, g1v, E1, NN1, 9);
    k_spmm<0, true><<<nblk(NN1, 4), B, 0, stream>>>(rp, spair, embUb, embAb, NUu,
                                                    nullptr, nullptr, nullptr, nullptr,
                                                    nullptr, nullptr, nullptr,
                                                    y1b, nullptr, nullptr, NN1);
    k_spmm<0, false><<<nblk(NN1, 4), B, 0, stream>>>(rp, spair, y1b, nullptr, 0,
                                                     nullptr, nullptr, nullptr, nullptr,
                                                     nullptr, nullptr, nullptr,
                                                     y2b, nullptr, nullptr, NN1);
    k_spmm<1, false><<<nblk(NN1, 4), B, 0, stream>>>(rp, spair, y2b, nullptr, NUu,
                                                     emb_user, emb_author, y1b, y2b,
                                                     oUserN, oAuthN, oAuthNb,
                                                     nullptr, nullptr, nullptr, NN1);

    // ========== atom_authors = normalize(g3 @ items0) ==========
    build_csr(g3r, g3c, g3v, E3, NAa, 5);
    k_spmm<2, false><<<nblk(NAa, 4), B, 0, stream>>>(rp, spair, items0b, nullptr, 0,
                                                     nullptr, nullptr, nullptr, nullptr,
                                                     nullptr, nullptr, nullptr,
                                                     nullptr, oAuthA, nullptr, NAa);

    // ========== atom_items = 0.5*normalize(g5 @ items0) + 0.5*items0 ==========
    build_csr(g5r, g5c, g5v, E5, NIi, 8);
    k_spmm<3, false><<<nblk(NIi, 4), B, 0, stream>>>(rp, spair, items0b, nullptr, 0,
                                                     nullptr, nullptr, nullptr, nullptr,
                                                     nullptr, nullptr, nullptr,
                                                     nullptr, oItemA, items0, NIi);

    // ========== non_atom_items = normalize(g4 @ non_atom_authors) ==========
    build_csr(g4r, g4c, g4v, E4, NIi, 8);
    k_spmm<2, false><<<nblk(NIi, 4), B, 0, stream>>>(rp, spair, oAuthNb, nullptr, 0,
                                                     nullptr, nullptr, nullptr, nullptr,
                                                     nullptr, nullptr, nullptr,
                                                     nullptr, oItemN, nullptr, NIi);
}